// Round 2
// baseline (1185.449 us; speedup 1.0000x reference)
//
#include <hip/hip_runtime.h>
#include <hip/hip_bf16.h>

// SparseMoE: B=4,S=2048 -> T=8192 tokens, D=1024, FF=4096, E=8, top-2.
// R2: global_load_lds (width-16) staging in both GEMMs (m97 structure,
// unpadded LDS tiles), float4 transpose, router fused with x->bf16 cvt.

#define T_TOK 8192
#define D_EMB 1024
#define DFF   4096
#define N_EXP 8
#define BM 128
#define BN 128
#define BK 64

typedef __attribute__((ext_vector_type(8))) short bf16x8;
typedef __attribute__((ext_vector_type(4))) float floatx4;
typedef unsigned short bf16_t;

__device__ __forceinline__ bf16_t f2bf(float f) {
  union { float f; unsigned u; } a; a.f = f;
  unsigned u = a.u;
  return (bf16_t)((u + 0x7fffu + ((u >> 16) & 1u)) >> 16);  // RNE
}

// async global->LDS, 16B per lane; lds base must be wave-uniform, HW writes
// lane l's data at ldsbase + l*16 (no padding allowed in the tile layout).
__device__ __forceinline__ void ld_lds16(const bf16_t* g, bf16_t* l) {
  __builtin_amdgcn_global_load_lds(
      (const __attribute__((address_space(1))) void*)g,
      (__attribute__((address_space(3))) void*)l, 16, 0, 0);
}

// ------------- transpose+cvt: in [E][K][N] f32 -> out [E][N][K] bf16 -------------
// 64x64 tiles, float4 loads, uint4 stores.
__global__ __launch_bounds__(256) void tcvt_k(const float* __restrict__ in,
                                              bf16_t* __restrict__ outp,
                                              int K, int N) {
  __shared__ bf16_t t[64][72];  // [n][k], +8 bf16 pad
  int e = blockIdx.z, n0 = blockIdx.x * 64, k0 = blockIdx.y * 64;
  int tid = threadIdx.x;
  const float* src = in + (size_t)e * K * N;
  int kr = tid >> 4;        // 0..15
  int nc = (tid & 15) * 4;  // 0..60
#pragma unroll
  for (int p = 0; p < 4; ++p) {
    int k = p * 16 + kr;
    float4 v = *(const float4*)(src + (size_t)(k0 + k) * N + n0 + nc);
    t[nc + 0][k] = f2bf(v.x);
    t[nc + 1][k] = f2bf(v.y);
    t[nc + 2][k] = f2bf(v.z);
    t[nc + 3][k] = f2bf(v.w);
  }
  __syncthreads();
  bf16_t* dst = outp + (size_t)e * K * N;  // [N][K]
  int nr = tid >> 3;       // 0..31
  int kc = (tid & 7) * 8;  // 0..56
#pragma unroll
  for (int p = 0; p < 2; ++p) {
    int n = p * 32 + nr;
    *(uint4*)(dst + (size_t)(n0 + n) * K + k0 + kc) = *(const uint4*)&t[n][kc];
  }
}

// ---------------- router (fused x->bf16 cvt) ----------------
__global__ __launch_bounds__(256) void router_k(
    const float* __restrict__ x, const float* __restrict__ nu,
    const float* __restrict__ wg, const float* __restrict__ bgp,
    const float* __restrict__ wn, const float* __restrict__ bnp,
    int* __restrict__ cnt, int* __restrict__ tok, float* __restrict__ gate,
    bf16_t* __restrict__ xb) {
  int t = blockIdx.x;
  int tid = threadIdx.x;
  float gl[8] = {0,0,0,0,0,0,0,0};
  float nl[8] = {0,0,0,0,0,0,0,0};
  const float* xr = x + (size_t)t * D_EMB;
  bf16_t* xbr = xb + (size_t)t * D_EMB;
  for (int i = tid; i < D_EMB; i += 256) {
    float xv = xr[i];
    xbr[i] = f2bf(xv);
    float4 a0 = *(const float4*)(wg + i * 8);
    float4 a1 = *(const float4*)(wg + i * 8 + 4);
    float4 c0 = *(const float4*)(wn + i * 8);
    float4 c1 = *(const float4*)(wn + i * 8 + 4);
    gl[0] += xv * a0.x; gl[1] += xv * a0.y; gl[2] += xv * a0.z; gl[3] += xv * a0.w;
    gl[4] += xv * a1.x; gl[5] += xv * a1.y; gl[6] += xv * a1.z; gl[7] += xv * a1.w;
    nl[0] += xv * c0.x; nl[1] += xv * c0.y; nl[2] += xv * c0.z; nl[3] += xv * c0.w;
    nl[4] += xv * c1.x; nl[5] += xv * c1.y; nl[6] += xv * c1.z; nl[7] += xv * c1.w;
  }
  __shared__ float red[4][16];
  int lane = tid & 63;
  int wv = tid >> 6;
#pragma unroll
  for (int o = 0; o < 16; ++o) {
    float v = (o < 8) ? gl[o] : nl[o - 8];
#pragma unroll
    for (int s = 32; s > 0; s >>= 1) v += __shfl_down(v, s, 64);
    if (lane == 0) red[wv][o] = v;
  }
  __syncthreads();
  if (tid == 0) {
    float noisy[8];
#pragma unroll
    for (int e = 0; e < 8; ++e) {
      float lg = red[0][e] + red[1][e] + red[2][e] + red[3][e] + bgp[e];
      float nz = red[0][8 + e] + red[1][8 + e] + red[2][8 + e] + red[3][8 + e] + bnp[e];
      float sp = fmaxf(nz, 0.f) + log1pf(expf(-fabsf(nz)));  // stable softplus
      noisy[e] = lg + nu[(size_t)t * 8 + e] * sp;
    }
    int e1 = 0;
#pragma unroll
    for (int e = 1; e < 8; ++e) if (noisy[e] > noisy[e1]) e1 = e;
    int e2 = -1;
#pragma unroll
    for (int e = 0; e < 8; ++e) {
      if (e == e1) continue;
      if (e2 < 0 || noisy[e] > noisy[e2]) e2 = e;
    }
    float d = expf(noisy[e2] - noisy[e1]);   // <= 1, no overflow
    float g1 = 1.f / (1.f + d);
    float g2 = d / (1.f + d);
    int p1 = atomicAdd(&cnt[e1], 1);
    tok[e1 * T_TOK + p1] = t; gate[e1 * T_TOK + p1] = g1;
    int p2 = atomicAdd(&cnt[e2], 1);
    tok[e2 * T_TOK + p2] = t; gate[e2 * T_TOK + p2] = g2;
  }
}

// ---------------- scan (8 experts) ----------------
__global__ void scan_k(const int* __restrict__ cnt, int* __restrict__ offs) {
  if (threadIdx.x == 0 && blockIdx.x == 0) {
    int a = 0;
    for (int e = 0; e < N_EXP; ++e) { offs[e] = a; a += cnt[e]; }
    offs[N_EXP] = a;
  }
}

// ---------------- GEMM1: h = relu(x_gathered @ w1 + b1), bf16 out ----------------
__global__ __launch_bounds__(256) void gemm1_k(
    const bf16_t* __restrict__ xb, const bf16_t* __restrict__ w1T,
    const float* __restrict__ b1p, const int* __restrict__ cnt,
    const int* __restrict__ offs, const int* __restrict__ tok,
    bf16_t* __restrict__ h) {
  const int NT = DFF / BN;    // 32
  const int MT = T_TOK / BM;  // 64
  int bid = blockIdx.x;
  int e = bid / (MT * NT);
  int rem = bid % (MT * NT);
  int mt = rem / NT;
  int nt = rem % NT;
  int cnte = cnt[e];
  if (mt * BM >= cnte) return;
  int rows = min(BM, cnte - mt * BM);

  __shared__ bf16_t As[BM][BK];   // unpadded: required by global_load_lds
  __shared__ bf16_t Bs[BN][BK];
  __shared__ int stok[BM];

  int tid = threadIdx.x;
  if (tid < BM) {
    int r = mt * BM + ((tid < rows) ? tid : rows - 1);
    stok[tid] = tok[e * T_TOK + r];
  }
  __syncthreads();

  int lane = tid & 63;
  int wv = tid >> 6;
  // staging map: wave wv stages rows [wv*32, wv*32+32), 4 insts of 8 rows;
  // lane l -> row +l/8, 16B chunk (l%8)
  int srow8 = lane >> 3;
  int schunk = (lane & 7) * 8;
  const bf16_t* aptr[4];
  const bf16_t* bptr[4];
#pragma unroll
  for (int it = 0; it < 4; ++it) {
    int r = wv * 32 + it * 8 + srow8;
    aptr[it] = xb + (size_t)stok[r] * D_EMB + schunk;
    bptr[it] = w1T + ((size_t)e * DFF + nt * BN + r) * D_EMB + schunk;
  }

  int m0 = (wv & 1) * 64;
  int n0 = (wv >> 1) * 64;
  int lm = lane & 15;
  int lq = lane >> 4;

  floatx4 acc[4][4];
#pragma unroll
  for (int i = 0; i < 4; ++i)
#pragma unroll
    for (int j = 0; j < 4; ++j)
#pragma unroll
      for (int r = 0; r < 4; ++r) acc[i][j][r] = 0.f;

  for (int kk = 0; kk < D_EMB; kk += BK) {
#pragma unroll
    for (int it = 0; it < 4; ++it) {
      ld_lds16(aptr[it] + kk, &As[wv * 32 + it * 8][0]);
      ld_lds16(bptr[it] + kk, &Bs[wv * 32 + it * 8][0]);
    }
    __syncthreads();
#pragma unroll
    for (int ks = 0; ks < BK; ks += 32) {
      bf16x8 af[4], bfr[4];
#pragma unroll
      for (int i = 0; i < 4; ++i)
        af[i] = *(const bf16x8*)&As[m0 + i * 16 + lm][ks + lq * 8];
#pragma unroll
      for (int j = 0; j < 4; ++j)
        bfr[j] = *(const bf16x8*)&Bs[n0 + j * 16 + lm][ks + lq * 8];
#pragma unroll
      for (int i = 0; i < 4; ++i)
#pragma unroll
        for (int j = 0; j < 4; ++j)
          acc[i][j] = __builtin_amdgcn_mfma_f32_16x16x32_bf16(af[i], bfr[j], acc[i][j], 0, 0, 0);
    }
    __syncthreads();
  }

  int hbase = offs[e] + mt * BM;
#pragma unroll
  for (int i = 0; i < 4; ++i) {
    int lr0 = m0 + i * 16 + lq * 4;
#pragma unroll
    for (int r = 0; r < 4; ++r) {
      if (lr0 + r < rows) {
        size_t hrow = (size_t)(hbase + lr0 + r) * DFF;
#pragma unroll
        for (int j = 0; j < 4; ++j) {
          int col = nt * BN + n0 + j * 16 + lm;
          float v = acc[i][j][r] + b1p[e * DFF + col];
          h[hrow + col] = f2bf(fmaxf(v, 0.f));
        }
      }
    }
  }
}

// ---------------- GEMM2: out[tok] += gate * (h @ w2 + b2) ----------------
__global__ __launch_bounds__(256) void gemm2_k(
    const bf16_t* __restrict__ h, const bf16_t* __restrict__ w2T,
    const float* __restrict__ b2p, const int* __restrict__ cnt,
    const int* __restrict__ offs, const int* __restrict__ tok,
    const float* __restrict__ gate, float* __restrict__ out) {
  const int NT = D_EMB / BN;  // 8
  const int MT = T_TOK / BM;  // 64
  int bid = blockIdx.x;
  int e = bid / (MT * NT);
  int rem = bid % (MT * NT);
  int mt = rem / NT;
  int nt = rem % NT;
  int cnte = cnt[e];
  if (mt * BM >= cnte) return;
  int rows = min(BM, cnte - mt * BM);

  __shared__ bf16_t As[BM][BK];
  __shared__ bf16_t Bs[BN][BK];
  __shared__ int stok[BM];
  __shared__ float sgate[BM];

  int tid = threadIdx.x;
  if (tid < BM) {
    int idx = e * T_TOK + mt * BM + ((tid < rows) ? tid : 0);
    stok[tid] = tok[idx];
    sgate[tid] = gate[idx];
  }

  int lane = tid & 63;
  int wv = tid >> 6;
  int srow8 = lane >> 3;
  int schunk = (lane & 7) * 8;
  int hbase0 = offs[e] + mt * BM;
  const bf16_t* aptr[4];
  const bf16_t* bptr[4];
#pragma unroll
  for (int it = 0; it < 4; ++it) {
    int r = wv * 32 + it * 8 + srow8;
    int rc = (r < rows) ? r : 0;  // clamp within expert's h region
    aptr[it] = h + (size_t)(hbase0 + rc) * DFF + schunk;
    bptr[it] = w2T + ((size_t)e * D_EMB + nt * BN + r) * DFF + schunk;
  }

  int m0 = (wv & 1) * 64;
  int n0 = (wv >> 1) * 64;
  int lm = lane & 15;
  int lq = lane >> 4;

  floatx4 acc[4][4];
#pragma unroll
  for (int i = 0; i < 4; ++i)
#pragma unroll
    for (int j = 0; j < 4; ++j)
#pragma unroll
      for (int r = 0; r < 4; ++r) acc[i][j][r] = 0.f;

  for (int kk = 0; kk < DFF; kk += BK) {
#pragma unroll
    for (int it = 0; it < 4; ++it) {
      ld_lds16(aptr[it] + kk, &As[wv * 32 + it * 8][0]);
      ld_lds16(bptr[it] + kk, &Bs[wv * 32 + it * 8][0]);
    }
    __syncthreads();
#pragma unroll
    for (int ks = 0; ks < BK; ks += 32) {
      bf16x8 af[4], bfr[4];
#pragma unroll
      for (int i = 0; i < 4; ++i)
        af[i] = *(const bf16x8*)&As[m0 + i * 16 + lm][ks + lq * 8];
#pragma unroll
      for (int j = 0; j < 4; ++j)
        bfr[j] = *(const bf16x8*)&Bs[n0 + j * 16 + lm][ks + lq * 8];
#pragma unroll
      for (int i = 0; i < 4; ++i)
#pragma unroll
        for (int j = 0; j < 4; ++j)
          acc[i][j] = __builtin_amdgcn_mfma_f32_16x16x32_bf16(af[i], bfr[j], acc[i][j], 0, 0, 0);
    }
    __syncthreads();
  }

#pragma unroll
  for (int i = 0; i < 4; ++i) {
    int lr0 = m0 + i * 16 + lq * 4;
#pragma unroll
    for (int r = 0; r < 4; ++r) {
      int lr = lr0 + r;
      if (lr < rows) {
        int t = stok[lr];
        float g = sgate[lr];
#pragma unroll
        for (int j = 0; j < 4; ++j) {
          int col = nt * BN + n0 + j * 16 + lm;
          float v = g * (acc[i][j][r] + b2p[e * D_EMB + col]);
          unsafeAtomicAdd(&out[(size_t)t * D_EMB + col], v);
        }
      }
    }
  }
}

extern "C" void kernel_launch(void* const* d_in, const int* in_sizes, int n_in,
                              void* d_out, int out_size, void* d_ws, size_t ws_size,
                              hipStream_t stream) {
  const float* x  = (const float*)d_in[0];
  const float* nu = (const float*)d_in[1];
  const float* wg = (const float*)d_in[2];
  const float* bg = (const float*)d_in[3];
  const float* wn = (const float*)d_in[4];
  const float* bn = (const float*)d_in[5];
  const float* w1 = (const float*)d_in[6];
  const float* b1 = (const float*)d_in[7];
  const float* w2 = (const float*)d_in[8];
  const float* b2 = (const float*)d_in[9];
  float* out = (float*)d_out;

  char* ws = (char*)d_ws;
  size_t o = 0;
  int* cnt  = (int*)(ws + o);          // 8 ints
  int* offs = cnt + 8;                 // 9 ints (within 256B header)
  o += 256;
  int*   tok  = (int*)(ws + o);   o += (size_t)N_EXP * T_TOK * 4;
  float* gate = (float*)(ws + o); o += (size_t)N_EXP * T_TOK * 4;
  bf16_t* xb  = (bf16_t*)(ws + o); o += (size_t)T_TOK * D_EMB * 2;
  bf16_t* w1T = (bf16_t*)(ws + o); o += (size_t)N_EXP * D_EMB * DFF * 2;
  bf16_t* w2T = (bf16_t*)(ws + o); o += (size_t)N_EXP * D_EMB * DFF * 2;
  bf16_t* h   = (bf16_t*)(ws + o); o += (size_t)2 * T_TOK * DFF * 2;
  (void)o; (void)ws_size; (void)in_sizes; (void)n_in;

  hipMemsetAsync(cnt, 0, 256, stream);
  hipMemsetAsync(out, 0, (size_t)out_size * sizeof(float), stream);

  tcvt_k<<<dim3(DFF / 64, D_EMB / 64, N_EXP), 256, 0, stream>>>(w1, w1T, D_EMB, DFF);
  tcvt_k<<<dim3(D_EMB / 64, DFF / 64, N_EXP), 256, 0, stream>>>(w2, w2T, DFF, D_EMB);
  router_k<<<T_TOK, 256, 0, stream>>>(x, nu, wg, bg, wn, bn, cnt, tok, gate, xb);
  scan_k<<<1, 64, 0, stream>>>(cnt, offs);
  gemm1_k<<<N_EXP * (T_TOK / BM) * (DFF / BN), 256, 0, stream>>>(xb, w1T, b1, cnt, offs, tok, h);
  gemm2_k<<<N_EXP * (T_TOK / BM) * (D_EMB / BN), 256, 0, stream>>>(h, w2T, b2, cnt, offs, tok, gate, out);
}

// Round 3
// 1103.651 us; speedup vs baseline: 1.0741x; 1.0741x over previous
//
#include <hip/hip_runtime.h>
#include <hip/hip_bf16.h>

// SparseMoE: B=4,S=2048 -> T=8192 tokens, D=1024, FF=4096, E=8, top-2.
// R3: global_load_lds staging + XOR-swizzled LDS chunk layout.
// Logical chunk c (16B) of tile row r lives at physical chunk c^(r&7):
// staging lane picks global chunk (l&7)^(l>>3); fragment reads XOR by row&7.
// Kills the R2 16-way ds_read_b128 conflicts (row stride 128B = 32 banks)
// while keeping the async-staging VALU savings.

#define T_TOK 8192
#define D_EMB 1024
#define DFF   4096
#define N_EXP 8
#define BM 128
#define BN 128
#define BK 64

typedef __attribute__((ext_vector_type(8))) short bf16x8;
typedef __attribute__((ext_vector_type(4))) float floatx4;
typedef unsigned short bf16_t;

__device__ __forceinline__ bf16_t f2bf(float f) {
  union { float f; unsigned u; } a; a.f = f;
  unsigned u = a.u;
  return (bf16_t)((u + 0x7fffu + ((u >> 16) & 1u)) >> 16);  // RNE
}

// async global->LDS, 16B per lane; lds base wave-uniform, HW writes lane l at
// ldsbase + l*16.
__device__ __forceinline__ void ld_lds16(const bf16_t* g, bf16_t* l) {
  __builtin_amdgcn_global_load_lds(
      (const __attribute__((address_space(1))) void*)g,
      (__attribute__((address_space(3))) void*)l, 16, 0, 0);
}

// ------------- transpose+cvt: in [E][K][N] f32 -> out [E][N][K] bf16 -------------
__global__ __launch_bounds__(256) void tcvt_k(const float* __restrict__ in,
                                              bf16_t* __restrict__ outp,
                                              int K, int N) {
  __shared__ bf16_t t[64][72];  // [n][k], +8 bf16 pad
  int e = blockIdx.z, n0 = blockIdx.x * 64, k0 = blockIdx.y * 64;
  int tid = threadIdx.x;
  const float* src = in + (size_t)e * K * N;
  int kr = tid >> 4;        // 0..15
  int nc = (tid & 15) * 4;  // 0..60
#pragma unroll
  for (int p = 0; p < 4; ++p) {
    int k = p * 16 + kr;
    float4 v = *(const float4*)(src + (size_t)(k0 + k) * N + n0 + nc);
    t[nc + 0][k] = f2bf(v.x);
    t[nc + 1][k] = f2bf(v.y);
    t[nc + 2][k] = f2bf(v.z);
    t[nc + 3][k] = f2bf(v.w);
  }
  __syncthreads();
  bf16_t* dst = outp + (size_t)e * K * N;  // [N][K]
  int nr = tid >> 3;       // 0..31
  int kc = (tid & 7) * 8;  // 0..56
#pragma unroll
  for (int p = 0; p < 2; ++p) {
    int n = p * 32 + nr;
    *(uint4*)(dst + (size_t)(n0 + n) * K + k0 + kc) = *(const uint4*)&t[n][kc];
  }
}

// ---------------- router (fused x->bf16 cvt) ----------------
__global__ __launch_bounds__(256) void router_k(
    const float* __restrict__ x, const float* __restrict__ nu,
    const float* __restrict__ wg, const float* __restrict__ bgp,
    const float* __restrict__ wn, const float* __restrict__ bnp,
    int* __restrict__ cnt, int* __restrict__ tok, float* __restrict__ gate,
    bf16_t* __restrict__ xb) {
  int t = blockIdx.x;
  int tid = threadIdx.x;
  float gl[8] = {0,0,0,0,0,0,0,0};
  float nl[8] = {0,0,0,0,0,0,0,0};
  const float* xr = x + (size_t)t * D_EMB;
  bf16_t* xbr = xb + (size_t)t * D_EMB;
  for (int i = tid; i < D_EMB; i += 256) {
    float xv = xr[i];
    xbr[i] = f2bf(xv);
    float4 a0 = *(const float4*)(wg + i * 8);
    float4 a1 = *(const float4*)(wg + i * 8 + 4);
    float4 c0 = *(const float4*)(wn + i * 8);
    float4 c1 = *(const float4*)(wn + i * 8 + 4);
    gl[0] += xv * a0.x; gl[1] += xv * a0.y; gl[2] += xv * a0.z; gl[3] += xv * a0.w;
    gl[4] += xv * a1.x; gl[5] += xv * a1.y; gl[6] += xv * a1.z; gl[7] += xv * a1.w;
    nl[0] += xv * c0.x; nl[1] += xv * c0.y; nl[2] += xv * c0.z; nl[3] += xv * c0.w;
    nl[4] += xv * c1.x; nl[5] += xv * c1.y; nl[6] += xv * c1.z; nl[7] += xv * c1.w;
  }
  __shared__ float red[4][16];
  int lane = tid & 63;
  int wv = tid >> 6;
#pragma unroll
  for (int o = 0; o < 16; ++o) {
    float v = (o < 8) ? gl[o] : nl[o - 8];
#pragma unroll
    for (int s = 32; s > 0; s >>= 1) v += __shfl_down(v, s, 64);
    if (lane == 0) red[wv][o] = v;
  }
  __syncthreads();
  if (tid == 0) {
    float noisy[8];
#pragma unroll
    for (int e = 0; e < 8; ++e) {
      float lg = red[0][e] + red[1][e] + red[2][e] + red[3][e] + bgp[e];
      float nz = red[0][8 + e] + red[1][8 + e] + red[2][8 + e] + red[3][8 + e] + bnp[e];
      float sp = fmaxf(nz, 0.f) + log1pf(expf(-fabsf(nz)));  // stable softplus
      noisy[e] = lg + nu[(size_t)t * 8 + e] * sp;
    }
    int e1 = 0;
#pragma unroll
    for (int e = 1; e < 8; ++e) if (noisy[e] > noisy[e1]) e1 = e;
    int e2 = -1;
#pragma unroll
    for (int e = 0; e < 8; ++e) {
      if (e == e1) continue;
      if (e2 < 0 || noisy[e] > noisy[e2]) e2 = e;
    }
    float d = expf(noisy[e2] - noisy[e1]);   // <= 1, no overflow
    float g1 = 1.f / (1.f + d);
    float g2 = d / (1.f + d);
    int p1 = atomicAdd(&cnt[e1], 1);
    tok[e1 * T_TOK + p1] = t; gate[e1 * T_TOK + p1] = g1;
    int p2 = atomicAdd(&cnt[e2], 1);
    tok[e2 * T_TOK + p2] = t; gate[e2 * T_TOK + p2] = g2;
  }
}

// ---------------- scan (8 experts) ----------------
__global__ void scan_k(const int* __restrict__ cnt, int* __restrict__ offs) {
  if (threadIdx.x == 0 && blockIdx.x == 0) {
    int a = 0;
    for (int e = 0; e < N_EXP; ++e) { offs[e] = a; a += cnt[e]; }
    offs[N_EXP] = a;
  }
}

// ---------------- GEMM1: h = relu(x_gathered @ w1 + b1), bf16 out ----------------
__global__ __launch_bounds__(256) void gemm1_k(
    const bf16_t* __restrict__ xb, const bf16_t* __restrict__ w1T,
    const float* __restrict__ b1p, const int* __restrict__ cnt,
    const int* __restrict__ offs, const int* __restrict__ tok,
    bf16_t* __restrict__ h) {
  const int NT = DFF / BN;    // 32
  const int MT = T_TOK / BM;  // 64
  int bid = blockIdx.x;
  int e = bid / (MT * NT);
  int rem = bid % (MT * NT);
  int mt = rem / NT;
  int nt = rem % NT;
  int cnte = cnt[e];
  if (mt * BM >= cnte) return;
  int rows = min(BM, cnte - mt * BM);

  __shared__ bf16_t As[BM][BK];   // unpadded; XOR-swizzled chunk layout
  __shared__ bf16_t Bs[BN][BK];
  __shared__ int stok[BM];

  int tid = threadIdx.x;
  if (tid < BM) {
    int r = mt * BM + ((tid < rows) ? tid : rows - 1);
    stok[tid] = tok[e * T_TOK + r];
  }
  __syncthreads();

  int lane = tid & 63;
  int wv = tid >> 6;
  // staging: wave wv stages rows [wv*32, wv*32+32), 4 insts of 8 rows.
  // lane l -> row +(l>>3), physical chunk l&7 holds global chunk (l&7)^(l>>3).
  int srow8 = lane >> 3;
  int schunk = ((lane & 7) ^ srow8) * 8;
  const bf16_t* aptr[4];
  const bf16_t* bptr[4];
#pragma unroll
  for (int it = 0; it < 4; ++it) {
    int r = wv * 32 + it * 8 + srow8;
    aptr[it] = xb + (size_t)stok[r] * D_EMB + schunk;
    bptr[it] = w1T + ((size_t)e * DFF + nt * BN + r) * D_EMB + schunk;
  }

  int m0 = (wv & 1) * 64;
  int n0 = (wv >> 1) * 64;
  int lm = lane & 15;
  int lq = lane >> 4;
  int sw = lm & 7;  // read-side swizzle (row&7 == lm&7 for rows m0+i*16+lm)

  floatx4 acc[4][4];
#pragma unroll
  for (int i = 0; i < 4; ++i)
#pragma unroll
    for (int j = 0; j < 4; ++j)
#pragma unroll
      for (int r = 0; r < 4; ++r) acc[i][j][r] = 0.f;

  for (int kk = 0; kk < D_EMB; kk += BK) {
#pragma unroll
    for (int it = 0; it < 4; ++it) {
      ld_lds16(aptr[it] + kk, &As[wv * 32 + it * 8][0]);
      ld_lds16(bptr[it] + kk, &Bs[wv * 32 + it * 8][0]);
    }
    __syncthreads();
#pragma unroll
    for (int ks = 0; ks < BK; ks += 32) {
      int pc = (((ks >> 3) + lq) ^ sw) * 8;  // physical column of logical chunk
      bf16x8 af[4], bfr[4];
#pragma unroll
      for (int i = 0; i < 4; ++i)
        af[i] = *(const bf16x8*)&As[m0 + i * 16 + lm][pc];
#pragma unroll
      for (int j = 0; j < 4; ++j)
        bfr[j] = *(const bf16x8*)&Bs[n0 + j * 16 + lm][pc];
#pragma unroll
      for (int i = 0; i < 4; ++i)
#pragma unroll
        for (int j = 0; j < 4; ++j)
          acc[i][j] = __builtin_amdgcn_mfma_f32_16x16x32_bf16(af[i], bfr[j], acc[i][j], 0, 0, 0);
    }
    __syncthreads();
  }

  int hbase = offs[e] + mt * BM;
#pragma unroll
  for (int i = 0; i < 4; ++i) {
    int lr0 = m0 + i * 16 + lq * 4;
#pragma unroll
    for (int r = 0; r < 4; ++r) {
      if (lr0 + r < rows) {
        size_t hrow = (size_t)(hbase + lr0 + r) * DFF;
#pragma unroll
        for (int j = 0; j < 4; ++j) {
          int col = nt * BN + n0 + j * 16 + lm;
          float v = acc[i][j][r] + b1p[e * DFF + col];
          h[hrow + col] = f2bf(fmaxf(v, 0.f));
        }
      }
    }
  }
}

// ---------------- GEMM2: out[tok] += gate * (h @ w2 + b2) ----------------
__global__ __launch_bounds__(256) void gemm2_k(
    const bf16_t* __restrict__ h, const bf16_t* __restrict__ w2T,
    const float* __restrict__ b2p, const int* __restrict__ cnt,
    const int* __restrict__ offs, const int* __restrict__ tok,
    const float* __restrict__ gate, float* __restrict__ out) {
  const int NT = D_EMB / BN;  // 8
  const int MT = T_TOK / BM;  // 64
  int bid = blockIdx.x;
  int e = bid / (MT * NT);
  int rem = bid % (MT * NT);
  int mt = rem / NT;
  int nt = rem % NT;
  int cnte = cnt[e];
  if (mt * BM >= cnte) return;
  int rows = min(BM, cnte - mt * BM);

  __shared__ bf16_t As[BM][BK];
  __shared__ bf16_t Bs[BN][BK];
  __shared__ int stok[BM];
  __shared__ float sgate[BM];

  int tid = threadIdx.x;
  if (tid < BM) {
    int idx = e * T_TOK + mt * BM + ((tid < rows) ? tid : 0);
    stok[tid] = tok[idx];
    sgate[tid] = gate[idx];
  }

  int lane = tid & 63;
  int wv = tid >> 6;
  int srow8 = lane >> 3;
  int schunk = ((lane & 7) ^ srow8) * 8;
  int hbase0 = offs[e] + mt * BM;
  const bf16_t* aptr[4];
  const bf16_t* bptr[4];
#pragma unroll
  for (int it = 0; it < 4; ++it) {
    int r = wv * 32 + it * 8 + srow8;
    int rc = (r < rows) ? r : 0;  // clamp within expert's h region
    aptr[it] = h + (size_t)(hbase0 + rc) * DFF + schunk;
    bptr[it] = w2T + ((size_t)e * D_EMB + nt * BN + r) * DFF + schunk;
  }

  int m0 = (wv & 1) * 64;
  int n0 = (wv >> 1) * 64;
  int lm = lane & 15;
  int lq = lane >> 4;
  int sw = lm & 7;

  floatx4 acc[4][4];
#pragma unroll
  for (int i = 0; i < 4; ++i)
#pragma unroll
    for (int j = 0; j < 4; ++j)
#pragma unroll
      for (int r = 0; r < 4; ++r) acc[i][j][r] = 0.f;

  for (int kk = 0; kk < DFF; kk += BK) {
#pragma unroll
    for (int it = 0; it < 4; ++it) {
      ld_lds16(aptr[it] + kk, &As[wv * 32 + it * 8][0]);
      ld_lds16(bptr[it] + kk, &Bs[wv * 32 + it * 8][0]);
    }
    __syncthreads();
#pragma unroll
    for (int ks = 0; ks < BK; ks += 32) {
      int pc = (((ks >> 3) + lq) ^ sw) * 8;
      bf16x8 af[4], bfr[4];
#pragma unroll
      for (int i = 0; i < 4; ++i)
        af[i] = *(const bf16x8*)&As[m0 + i * 16 + lm][pc];
#pragma unroll
      for (int j = 0; j < 4; ++j)
        bfr[j] = *(const bf16x8*)&Bs[n0 + j * 16 + lm][pc];
#pragma unroll
      for (int i = 0; i < 4; ++i)
#pragma unroll
        for (int j = 0; j < 4; ++j)
          acc[i][j] = __builtin_amdgcn_mfma_f32_16x16x32_bf16(af[i], bfr[j], acc[i][j], 0, 0, 0);
    }
    __syncthreads();
  }

#pragma unroll
  for (int i = 0; i < 4; ++i) {
    int lr0 = m0 + i * 16 + lq * 4;
#pragma unroll
    for (int r = 0; r < 4; ++r) {
      int lr = lr0 + r;
      if (lr < rows) {
        int t = stok[lr];
        float g = sgate[lr];
#pragma unroll
        for (int j = 0; j < 4; ++j) {
          int col = nt * BN + n0 + j * 16 + lm;
          float v = g * (acc[i][j][r] + b2p[e * D_EMB + col]);
          unsafeAtomicAdd(&out[(size_t)t * D_EMB + col], v);
        }
      }
    }
  }
}

extern "C" void kernel_launch(void* const* d_in, const int* in_sizes, int n_in,
                              void* d_out, int out_size, void* d_ws, size_t ws_size,
                              hipStream_t stream) {
  const float* x  = (const float*)d_in[0];
  const float* nu = (const float*)d_in[1];
  const float* wg = (const float*)d_in[2];
  const float* bg = (const float*)d_in[3];
  const float* wn = (const float*)d_in[4];
  const float* bn = (const float*)d_in[5];
  const float* w1 = (const float*)d_in[6];
  const float* b1 = (const float*)d_in[7];
  const float* w2 = (const float*)d_in[8];
  const float* b2 = (const float*)d_in[9];
  float* out = (float*)d_out;

  char* ws = (char*)d_ws;
  size_t o = 0;
  int* cnt  = (int*)(ws + o);          // 8 ints
  int* offs = cnt + 8;                 // 9 ints (within 256B header)
  o += 256;
  int*   tok  = (int*)(ws + o);   o += (size_t)N_EXP * T_TOK * 4;
  float* gate = (float*)(ws + o); o += (size_t)N_EXP * T_TOK * 4;
  bf16_t* xb  = (bf16_t*)(ws + o); o += (size_t)T_TOK * D_EMB * 2;
  bf16_t* w1T = (bf16_t*)(ws + o); o += (size_t)N_EXP * D_EMB * DFF * 2;
  bf16_t* w2T = (bf16_t*)(ws + o); o += (size_t)N_EXP * D_EMB * DFF * 2;
  bf16_t* h   = (bf16_t*)(ws + o); o += (size_t)2 * T_TOK * DFF * 2;
  (void)o; (void)ws_size; (void)in_sizes; (void)n_in;

  hipMemsetAsync(cnt, 0, 256, stream);
  hipMemsetAsync(out, 0, (size_t)out_size * sizeof(float), stream);

  tcvt_k<<<dim3(DFF / 64, D_EMB / 64, N_EXP), 256, 0, stream>>>(w1, w1T, D_EMB, DFF);
  tcvt_k<<<dim3(D_EMB / 64, DFF / 64, N_EXP), 256, 0, stream>>>(w2, w2T, DFF, D_EMB);
  router_k<<<T_TOK, 256, 0, stream>>>(x, nu, wg, bg, wn, bn, cnt, tok, gate, xb);
  scan_k<<<1, 64, 0, stream>>>(cnt, offs);
  gemm1_k<<<N_EXP * (T_TOK / BM) * (DFF / BN), 256, 0, stream>>>(xb, w1T, b1, cnt, offs, tok, h);
  gemm2_k<<<N_EXP * (T_TOK / BM) * (D_EMB / BN), 256, 0, stream>>>(h, w2T, b2, cnt, offs, tok, gate, out);
}